// Round 5
// baseline (1060.971 us; speedup 1.0000x reference)
//
#include <hip/hip_runtime.h>
#include <math.h>

#define NN 100000
#define NE 3200000
#define NG 1024
#define FDIM 128
#define NFC1 64
#define NFC2 10

#define BSHIFT 9
#define NBUCK 196   // ceil(NN/512)
#define CAP 20480   // mean 16384, sigma ~127 -> 32-sigma headroom
#define EPB 16      // edges per thread in bin_kernel

// ---------------- pass 1: bin edges into 196 coarse buckets ----------------
// Packed value: (dst & 511) << 17 | src   (src < 2^17, dst_local < 2^9)
__global__ __launch_bounds__(256) void bin_kernel(const int* __restrict__ src,
                                                  const int* __restrict__ dst,
                                                  int* __restrict__ gcursor,
                                                  int* __restrict__ staging) {
  __shared__ int hist[NBUCK];
  __shared__ int base[NBUCK];
  int t = threadIdx.x;
  for (int i = t; i < NBUCK; i += 256) hist[i] = 0;
  __syncthreads();
  size_t e0 = (size_t)blockIdx.x * (256 * EPB);
  int bk[EPB], rank[EPB], val[EPB];
#pragma unroll
  for (int j = 0; j < EPB; ++j) {
    size_t e = e0 + (size_t)j * 256 + t;
    if (e < NE) {
      int d = dst[e];
      int s = src[e];
      bk[j] = d >> BSHIFT;
      val[j] = ((d & 511) << 17) | s;
      rank[j] = atomicAdd(&hist[bk[j]], 1);
    } else {
      bk[j] = -1;
    }
  }
  __syncthreads();
  for (int i = t; i < NBUCK; i += 256) base[i] = atomicAdd(&gcursor[i], hist[i]);
  __syncthreads();
#pragma unroll
  for (int j = 0; j < EPB; ++j) {
    if (bk[j] >= 0) {
      int pos = base[bk[j]] + rank[j];
      if (pos < CAP) staging[(size_t)bk[j] * CAP + pos] = val[j];
    }
  }
}

// ---------------- pass 2: per-bucket CSR finalize (scan fused in) ----------------
__global__ __launch_bounds__(256) void build_kernel(const int* __restrict__ staging,
                                                    const int* __restrict__ gcursor,
                                                    int* __restrict__ row_off,
                                                    int* __restrict__ esrc) {
  __shared__ int ncnt[512];
  __shared__ int noff[513];
  __shared__ int part[256];
  __shared__ int sscan[256];
  int b = blockIdx.x, t = threadIdx.x;
  // inline exclusive scan of bucket counts to get this block's edge base
  int gv = (t < NBUCK) ? gcursor[t] : 0;
  sscan[t] = gv;
  __syncthreads();
  for (int st = 1; st < 256; st <<= 1) {
    int u = (t >= st) ? sscan[t - st] : 0;
    __syncthreads();
    sscan[t] += u;
    __syncthreads();
  }
  int cnt = gcursor[b];
  int ebase = sscan[b] - cnt;  // exclusive prefix
  int nbase = b << BSHIFT;
  ncnt[t] = 0;
  ncnt[t + 256] = 0;
  __syncthreads();
  const int* sp = staging + (size_t)b * CAP;
  for (int i = t; i < cnt; i += 256) {
    int dl = sp[i] >> 17;
    atomicAdd(&ncnt[dl], 1);
  }
  __syncthreads();
  int a0 = ncnt[2 * t], a1 = ncnt[2 * t + 1];
  part[t] = a0 + a1;
  __syncthreads();
  for (int st = 1; st < 256; st <<= 1) {
    int u = (t >= st) ? part[t - st] : 0;
    __syncthreads();
    part[t] += u;
    __syncthreads();
  }
  int excl = (t > 0) ? part[t - 1] : 0;
  noff[2 * t] = excl;
  noff[2 * t + 1] = excl + a0;
  if (t == 255) noff[512] = part[255];
  __syncthreads();
  for (int i = t; i <= 512; i += 256) {
    int n = nbase + i;
    if (n <= NN) row_off[n] = ebase + noff[i];
  }
  // reuse ncnt as write cursors
  ncnt[2 * t] = noff[2 * t];
  ncnt[2 * t + 1] = noff[2 * t + 1];
  __syncthreads();
  for (int i = t; i < cnt; i += 256) {
    int v = sp[i];
    int dl = v >> 17;
    int pos = atomicAdd(&ncnt[dl], 1);
    esrc[ebase + pos] = v & 0x1FFFF;
  }
}

// ---------------- fused conv layer: out = relu(gather(xin)@W + bias) ----------------
// 512 threads = 8 waves; 64 dst nodes per block. NO inter-wave barrier:
// wave w's LDS region (columns r in [8w, 8w+8)) is written and read only by
// wave w, so waves pipeline independently -- while one wave is in its GEMM
// (VALU) phase, others keep the VMEM pipe full with gathers.
// GEMM is split-k within the wave: lanes 0-31 accumulate k=0..63, lanes 32-63
// k=64..127 (one W float4 load instruction covers two k-rows), combined by a
// single shfl_down(32) at the end.
__global__ __launch_bounds__(512) void conv_fused(const float2* __restrict__ xin,
                                                  const int* __restrict__ row_off,
                                                  const int* __restrict__ esrc,
                                                  const float* __restrict__ W,
                                                  const float* __restrict__ bias,
                                                  float* __restrict__ out) {
  __shared__ __align__(16) float aT[128 * 68];
  int t = threadIdx.x;
  int w = t >> 6;
  int lane = t & 63;
  int nodebase = blockIdx.x * 64;
  int r0 = w * 8;

  // ---- phase 1: gather-aggregate 8 nodes for this wave ----
  for (int i = 0; i < 8; ++i) {
    int r = r0 + i;
    int node = nodebase + r;
    int beg = 0, end = 0;
    if (node < NN) {
      beg = __builtin_amdgcn_readfirstlane(row_off[node]);
      end = __builtin_amdgcn_readfirstlane(row_off[node + 1]);
    }
    float2 acc = make_float2(0.f, 0.f);
    int e = beg;
    for (; e + 8 <= end; e += 8) {
      int i0 = __builtin_amdgcn_readfirstlane(esrc[e + 0]);
      int i1 = __builtin_amdgcn_readfirstlane(esrc[e + 1]);
      int i2 = __builtin_amdgcn_readfirstlane(esrc[e + 2]);
      int i3 = __builtin_amdgcn_readfirstlane(esrc[e + 3]);
      int i4 = __builtin_amdgcn_readfirstlane(esrc[e + 4]);
      int i5 = __builtin_amdgcn_readfirstlane(esrc[e + 5]);
      int i6 = __builtin_amdgcn_readfirstlane(esrc[e + 6]);
      int i7 = __builtin_amdgcn_readfirstlane(esrc[e + 7]);
      float2 v0 = xin[(size_t)i0 * 64 + lane];
      float2 v1 = xin[(size_t)i1 * 64 + lane];
      float2 v2 = xin[(size_t)i2 * 64 + lane];
      float2 v3 = xin[(size_t)i3 * 64 + lane];
      float2 v4 = xin[(size_t)i4 * 64 + lane];
      float2 v5 = xin[(size_t)i5 * 64 + lane];
      float2 v6 = xin[(size_t)i6 * 64 + lane];
      float2 v7 = xin[(size_t)i7 * 64 + lane];
      acc.x += ((v0.x + v1.x) + (v2.x + v3.x)) + ((v4.x + v5.x) + (v6.x + v7.x));
      acc.y += ((v0.y + v1.y) + (v2.y + v3.y)) + ((v4.y + v5.y) + (v6.y + v7.y));
    }
    for (; e < end; ++e) {
      int i0 = __builtin_amdgcn_readfirstlane(esrc[e]);
      float2 v0 = xin[(size_t)i0 * 64 + lane];
      acc.x += v0.x;
      acc.y += v0.y;
    }
    aT[(2 * lane + 0) * 68 + r] = acc.x;
    aT[(2 * lane + 1) * 68 + r] = acc.y;
  }
  // no __syncthreads: LDS region is wave-private; compiler orders the
  // ds_write -> ds_read dependency via lgkmcnt.

  // ---- phase 2: GEMM 8 rows x 128 cols, split-k across half-waves ----
  int kh = lane >> 5;   // k-half: 0 -> k in [0,64), 1 -> [64,128)
  int c = lane & 31;    // cols 4c..4c+3

  float acc[8][4];
#pragma unroll
  for (int r = 0; r < 8; ++r)
#pragma unroll
    for (int j = 0; j < 4; ++j) acc[r][j] = 0.f;

#pragma unroll 4
  for (int kk = 0; kk < 64; ++kk) {
    int k = kh * 64 + kk;
    float4 bv = *(const float4*)(W + k * FDIM + c * 4);
    const float* ap = &aT[k * 68 + r0];
    float4 a0 = *(const float4*)(ap);
    float4 a1 = *(const float4*)(ap + 4);
    float ar[8] = {a0.x, a0.y, a0.z, a0.w, a1.x, a1.y, a1.z, a1.w};
#pragma unroll
    for (int r = 0; r < 8; ++r) {
      acc[r][0] += ar[r] * bv.x;
      acc[r][1] += ar[r] * bv.y;
      acc[r][2] += ar[r] * bv.z;
      acc[r][3] += ar[r] * bv.w;
    }
  }

  // combine k-halves: lanes 0-31 pick up lanes 32-63's partial sums
#pragma unroll
  for (int r = 0; r < 8; ++r)
#pragma unroll
    for (int j = 0; j < 4; ++j)
      acc[r][j] += __shfl_down(acc[r][j], 32, 64);

  if (kh == 0) {
    float4 b4 = *(const float4*)(bias + c * 4);
#pragma unroll
    for (int r = 0; r < 8; ++r) {
      int row = nodebase + r0 + r;
      if (row < NN) {
        float4 o;
        o.x = fmaxf(acc[r][0] + b4.x, 0.f);
        o.y = fmaxf(acc[r][1] + b4.y, 0.f);
        o.z = fmaxf(acc[r][2] + b4.z, 0.f);
        o.w = fmaxf(acc[r][3] + b4.w, 0.f);
        *(float4*)(out + (size_t)row * FDIM + c * 4) = o;
      }
    }
  }
}

// ---------------- fused global pool + FC1 + FC2 + softmax ----------------
__device__ int lower_bound_dev(const int* __restrict__ arr, int n, int val) {
  int lo = 0, hi = n;
  while (lo < hi) {
    int mid = (lo + hi) >> 1;
    if (arr[mid] < val) lo = mid + 1; else hi = mid;
  }
  return lo;
}

__global__ __launch_bounds__(128) void pool_head(const float* __restrict__ x,
                                                 const int* __restrict__ batching,
                                                 const float* __restrict__ Wf1,
                                                 const float* __restrict__ bf1,
                                                 const float* __restrict__ Wf2,
                                                 const float* __restrict__ bf2,
                                                 float* __restrict__ out) {
  __shared__ int se, ee;
  __shared__ float gl[128];
  __shared__ float hl[64];
  __shared__ float ol[10];
  __shared__ float red[2];
  int gid = blockIdx.x, t = threadIdx.x;
  if (t == 0) {
    se = lower_bound_dev(batching, NN, gid);
    ee = lower_bound_dev(batching, NN, gid + 1);
  }
  __syncthreads();
  float acc = 0.f;
  for (int n = se; n < ee; ++n) acc += x[(size_t)n * FDIM + t];
  gl[t] = acc;
  __syncthreads();
  if (t < NFC1) {
    float h = bf1[t];
    for (int f = 0; f < 128; ++f) h += gl[f] * Wf1[f * NFC1 + t];
    hl[t] = h;
  }
  __syncthreads();
  if (t < NFC2) {
    float o = bf2[t];
    for (int i = 0; i < NFC1; ++i) o += hl[i] * Wf2[i * NFC2 + t];
    ol[t] = o;
  }
  __syncthreads();
  if (t == 0) {
    float m = ol[0];
    for (int i = 1; i < NFC2; ++i) m = fmaxf(m, ol[i]);
    float s = 0.f;
    for (int i = 0; i < NFC2; ++i) s += expf(ol[i] - m);
    red[0] = m;
    red[1] = s;
  }
  __syncthreads();
  if (t < NFC2) out[(size_t)gid * NFC2 + t] = expf(ol[t] - red[0]) / red[1];
}

extern "C" void kernel_launch(void* const* d_in, const int* in_sizes, int n_in,
                              void* d_out, int out_size, void* d_ws, size_t ws_size,
                              hipStream_t stream) {
  const float* node_attr = (const float*)d_in[0];
  const float* Wc = (const float*)d_in[1];   // [3][128][128]
  const float* bc = (const float*)d_in[2];   // [3][128]
  const float* Wf1 = (const float*)d_in[3];  // [128][64]
  const float* bf1 = (const float*)d_in[4];
  const float* Wf2 = (const float*)d_in[5];  // [64][10]
  const float* bf2 = (const float*)d_in[6];
  const int* src = (const int*)d_in[7];
  const int* dst = (const int*)d_in[8];
  const int* batching = (const int*)d_in[9];
  float* out = (float*)d_out;

  char* wsp = (char*)d_ws;
  size_t off = 0;
  auto alloc = [&](size_t bytes) -> void* {
    void* p = wsp + off;
    off += (bytes + 255) & ~(size_t)255;
    return p;
  };
  int* row_off = (int*)alloc((size_t)(NN + 1) * sizeof(int));
  int* gcursor = (int*)alloc(NBUCK * sizeof(int));
  int* esrc = (int*)alloc((size_t)NE * sizeof(int));
  float* bufA = (float*)alloc((size_t)NN * FDIM * sizeof(float));
  float* bufB = (float*)alloc((size_t)NN * FDIM * sizeof(float));
  // staging (16.1 MB) aliases bufB: staging is dead before layer-2 writes bufB
  int* staging = (int*)bufB;

  // CSR build via 2-level counting sort
  hipMemsetAsync(gcursor, 0, NBUCK * sizeof(int), stream);
  bin_kernel<<<(NE + 256 * EPB - 1) / (256 * EPB), 256, 0, stream>>>(src, dst, gcursor, staging);
  build_kernel<<<NBUCK, 256, 0, stream>>>(staging, gcursor, row_off, esrc);

  // fused conv layers: gather -> LDS -> GEMM -> relu -> store
  conv_fused<<<(NN + 63) / 64, 512, 0, stream>>>((const float2*)node_attr, row_off, esrc,
                                                 Wc, bc, bufA);
  conv_fused<<<(NN + 63) / 64, 512, 0, stream>>>((const float2*)bufA, row_off, esrc,
                                                 Wc + 16384, bc + 128, bufB);
  conv_fused<<<(NN + 63) / 64, 512, 0, stream>>>((const float2*)bufB, row_off, esrc,
                                                 Wc + 32768, bc + 256, bufA);

  // fused pool + head
  pool_head<<<NG, 128, 0, stream>>>(bufA, batching, Wf1, bf1, Wf2, bf2, out);
}